// Round 5
// baseline (236.153 us; speedup 1.0000x reference)
//
#include <hip/hip_runtime.h>
#include <cmath>

// x,y: (16,3,512,512) f32. Fused separable-Gaussian SSIM, scalar mean output.
// Row-streaming: fully-unrolled 8 row-pairs, mod-12 static register ring (x,y),
// products recomputed in v-conv, h-conv via b128 reads of a 21KB LDS row-pair.
constexpr int IMG_H = 512;
constexpr int IMG_W = 512;
constexpr int PLANES = 48;
constexpr int R_OUT = 16;               // output rows per block (8 pairs)
constexpr int BANDS = IMG_H / R_OUT;    // 32
constexpr int PSTR = 528;               // padded row: col c stored at p = c+6
constexpr long long TOTAL_PIX = (long long)PLANES * IMG_H * IMG_W;

struct GWin { float g[11]; };

__global__ __launch_bounds__(256)
void ssim_stream2_kernel(const float* __restrict__ x,
                         const float* __restrict__ y,
                         double* __restrict__ accum,
                         GWin win)
{
    __shared__ __align__(16) float hbuf[2][5][PSTR];  // one row-pair of v-conv'd {x,y,xx,yy,xy}
    __shared__ float wsum[4];

    const int tid   = threadIdx.x;
    const int band  = blockIdx.x & (BANDS - 1);
    const int plane = blockIdx.x >> 5;
    const int r0    = band * R_OUT;
    const int c0    = tid * 2;           // v-pass: 2 columns per thread

    const float* __restrict__ xp = x + (size_t)plane * (IMG_H * IMG_W);
    const float* __restrict__ yp = y + (size_t)plane * (IMG_H * IMG_W);

    // zero horizontal halo slots once: p in [0,6) and [518,528), both rows, 5 fields
    if (tid < 160) {
        int w  = tid & 15;
        int bf = tid >> 4;              // 0..9 -> row bf/5, field bf%5
        int p  = (w < 6) ? w : (512 + w);   // 0..5, 518..527
        hbuf[bf / 5][bf % 5][p] = 0.f;
    }
    // (ordered before any h-read by the first in-loop __syncthreads)

    // 12-slot register ring of x,y rows (float2 per thread = 48 VGPRs), static idx only
    float2 xr[12], yr[12];

    auto load2 = [&](const float* __restrict__ base, int i) -> float2 {
        int gr = r0 - 5 + i;            // input row for ring index i
        if ((unsigned)gr < (unsigned)IMG_H)
            return *(const float2*)(base + (size_t)gr * IMG_W + c0);
        return make_float2(0.f, 0.f);
    };

#pragma unroll
    for (int i = 0; i < 10; ++i) {
        xr[i] = load2(xp, i);
        yr[i] = load2(yp, i);
    }

    float lsum = 0.f;

#pragma unroll
    for (int p = 0; p < 8; ++p) {
        // bring in the two input rows this pair needs (slots (2p+10)%12, (2p+11)%12)
        {
            const int i0 = 2 * p + 10, i1 = 2 * p + 11;
            xr[i0 % 12] = load2(xp, i0);  yr[i0 % 12] = load2(yp, i0);
            xr[i1 % 12] = load2(xp, i1);  yr[i1 % 12] = load2(yp, i1);
        }

        // vertical 11-tap conv for output rows 2p and 2p+1; products recomputed
#pragma unroll
        for (int r = 0; r < 2; ++r) {
            float2 vx{0,0}, vy{0,0}, vxx{0,0}, vyy{0,0}, vxy{0,0};
#pragma unroll
            for (int k = 0; k < 11; ++k) {
                const int s = (2 * p + r + k) % 12;   // compile-time
                const float g = win.g[k];
                const float2 xv = xr[s], yv = yr[s];
                vx.x  += g * xv.x;          vx.y  += g * xv.y;
                vy.x  += g * yv.x;          vy.y  += g * yv.y;
                vxx.x += g * (xv.x * xv.x); vxx.y += g * (xv.y * xv.y);
                vyy.x += g * (yv.x * yv.x); vyy.y += g * (yv.y * yv.y);
                vxy.x += g * (xv.x * yv.x); vxy.y += g * (xv.y * yv.y);
            }
            float* hb = &hbuf[r][0][0];
            hb[0 * PSTR + 6 + c0] = vx.x;   hb[0 * PSTR + 7 + c0] = vx.y;
            hb[1 * PSTR + 6 + c0] = vy.x;   hb[1 * PSTR + 7 + c0] = vy.y;
            hb[2 * PSTR + 6 + c0] = vxx.x;  hb[2 * PSTR + 7 + c0] = vxx.y;
            hb[3 * PSTR + 6 + c0] = vyy.x;  hb[3 * PSTR + 7 + c0] = vyy.y;
            hb[4 * PSTR + 6 + c0] = vxy.x;  hb[4 * PSTR + 7 + c0] = vxy.y;
        }

        __syncthreads();

        // horizontal 11-tap conv: thread -> row rw (0/1), 4 cols 4q..4q+3, b128 reads
        {
            const int rw = tid >> 7;
            const int q  = tid & 127;
            float m[5][4];
#pragma unroll
            for (int f = 0; f < 5; ++f) {
                const float4* rowv = (const float4*)&hbuf[rw][f][0];
                float4 a = rowv[q];
                float4 b = rowv[q + 1];
                float4 c = rowv[q + 2];
                float4 d = rowv[q + 3];
                float w16[16] = { a.x, a.y, a.z, a.w,  b.x, b.y, b.z, b.w,
                                  c.x, c.y, c.z, c.w,  d.x, d.y, d.z, d.w };
#pragma unroll
                for (int j = 0; j < 4; ++j) {
                    float s = 0.f;
#pragma unroll
                    for (int k = 0; k < 11; ++k) s += win.g[k] * w16[j + k + 1];
                    m[f][j] = s;
                }
            }
#pragma unroll
            for (int u = 0; u < 4; ++u) {
                float mx  = m[0][u];
                float my  = m[1][u];
                float mxx = m[2][u];
                float myy = m[3][u];
                float mxy = m[4][u];
                float mu_x_sq = mx * mx;
                float mu_y_sq = my * my;
                float mu_xy   = mx * my;
                float sig_x  = mxx - mu_x_sq;
                float sig_y  = myy - mu_y_sq;
                float sig_xy = mxy - mu_xy;
                const float C1 = 0.01f * 0.01f;
                const float C2 = 0.03f * 0.03f;
                float n = (2.f * mu_xy + C1) * (2.f * sig_xy + C2);
                float d = (mu_x_sq + mu_y_sq + C1) * (sig_x + sig_y + C2);
                lsum += n / (d + 1e-8f);
            }
        }

        __syncthreads();   // protect hbuf before next pair's writes
    }

    // block reduction
#pragma unroll
    for (int off = 32; off; off >>= 1) lsum += __shfl_down(lsum, off);
    if ((tid & 63) == 0) wsum[tid >> 6] = lsum;
    __syncthreads();
    if (tid == 0)
        atomicAdd(accum, (double)(wsum[0] + wsum[1] + wsum[2] + wsum[3]));
}

__global__ void ssim_finalize_kernel(const double* __restrict__ accum,
                                     float* __restrict__ out)
{
    out[0] = (float)(accum[0] / (double)TOTAL_PIX);
}

extern "C" void kernel_launch(void* const* d_in, const int* in_sizes, int n_in,
                              void* d_out, int out_size, void* d_ws, size_t ws_size,
                              hipStream_t stream) {
    const float* x = (const float*)d_in[0];
    const float* y = (const float*)d_in[1];
    float* out = (float*)d_out;
    double* accum = (double*)d_ws;

    GWin win;
    {
        double g[11], s = 0.0;
        for (int i = 0; i < 11; ++i) {
            double d = (double)i - 5.0;
            g[i] = std::exp(-(d * d) / (2.0 * 1.5 * 1.5));
            s += g[i];
        }
        for (int i = 0; i < 11; ++i) win.g[i] = (float)(g[i] / s);
    }

    hipMemsetAsync(d_ws, 0, sizeof(double), stream);

    const int nblocks = PLANES * BANDS;  // 1536
    ssim_stream2_kernel<<<nblocks, 256, 0, stream>>>(x, y, accum, win);
    ssim_finalize_kernel<<<1, 1, 0, stream>>>(accum, out);
}

// Round 6
// 99.334 us; speedup vs baseline: 2.3774x; 2.3774x over previous
//
#include <hip/hip_runtime.h>
#include <cmath>

// x,y: (16,3,512,512) f32. Fused separable-Gaussian SSIM, scalar mean output.
// Row-streaming, pair-processed: rolled loop (no forced occupancy, no full
// unroll), 12-slot static ring of x,y rows, shared products in v-conv,
// b128 sliding-window h-conv on a 21KB LDS row-pair.
constexpr int IMG_H = 512;
constexpr int IMG_W = 512;
constexpr int PLANES = 48;
constexpr int R_OUT = 16;               // output rows per block (8 pairs)
constexpr int BANDS = IMG_H / R_OUT;    // 32
constexpr int PSTR = 528;               // padded row: col c stored at p = c+6
constexpr long long TOTAL_PIX = (long long)PLANES * IMG_H * IMG_W;

struct GWin { float g[11]; };

__global__ __launch_bounds__(256)
void ssim_pair_kernel(const float* __restrict__ x,
                      const float* __restrict__ y,
                      double* __restrict__ accum,
                      GWin win)
{
    __shared__ __align__(16) float hbuf[2][5][PSTR];  // v-conv'd row pair, 5 fields
    __shared__ float wsum[4];

    const int tid   = threadIdx.x;
    const int band  = blockIdx.x & (BANDS - 1);
    const int plane = blockIdx.x >> 5;
    const int r0    = band * R_OUT;
    const int c0    = tid * 2;           // v-pass: 2 columns per thread

    const float* __restrict__ xp = x + (size_t)plane * (IMG_H * IMG_W);
    const float* __restrict__ yp = y + (size_t)plane * (IMG_H * IMG_W);

    // zero horizontal halo slots once: p in [0,6) and [518,528), 2 rows x 5 fields
    if (tid < 160) {
        int w  = tid & 15;
        int bf = tid >> 4;                  // 0..9
        int p  = (w < 6) ? w : (512 + w);   // 0..5, 518..527
        hbuf[bf / 5][bf % 5][p] = 0.f;
    }
    // (ordered before any h-read by the first in-loop __syncthreads)

    // 12-slot register ring of x,y rows; all indices compile-time static
    float2 xr[12], yr[12];

    auto load2 = [&](const float* __restrict__ base, int i) -> float2 {
        int gr = r0 - 5 + i;               // input row for ring position i
        if ((unsigned)gr < (unsigned)IMG_H)
            return *(const float2*)(base + (size_t)gr * IMG_W + c0);
        return make_float2(0.f, 0.f);
    };

#pragma unroll
    for (int i = 0; i < 10; ++i) {
        xr[i] = load2(xp, i);
        yr[i] = load2(yp, i);
    }

    float lsum = 0.f;

#pragma unroll 1
    for (int p = 0; p < 8; ++p) {
        const int ibase = 2 * p;           // runtime, only feeds load row index
        xr[10] = load2(xp, ibase + 10);  yr[10] = load2(yp, ibase + 10);
        xr[11] = load2(xp, ibase + 11);  yr[11] = load2(yp, ibase + 11);

        // vertical 11-tap conv of rows 2p (slots 0..10) and 2p+1 (slots 1..11),
        // products computed once per input row
        {
            float2 vx[2], vy[2], vxx[2], vyy[2], vxy[2];
#pragma unroll
            for (int r = 0; r < 2; ++r) {
                vx[r] = vy[r] = vxx[r] = vyy[r] = vxy[r] = make_float2(0.f, 0.f);
            }
#pragma unroll
            for (int k = 0; k < 12; ++k) {
                const float2 xv = xr[k], yv = yr[k];
                const float2 pxx = make_float2(xv.x * xv.x, xv.y * xv.y);
                const float2 pyy = make_float2(yv.x * yv.x, yv.y * yv.y);
                const float2 pxy = make_float2(xv.x * yv.x, xv.y * yv.y);
                if (k < 11) {
                    const float g = win.g[k];
                    vx[0].x  += g * xv.x;   vx[0].y  += g * xv.y;
                    vy[0].x  += g * yv.x;   vy[0].y  += g * yv.y;
                    vxx[0].x += g * pxx.x;  vxx[0].y += g * pxx.y;
                    vyy[0].x += g * pyy.x;  vyy[0].y += g * pyy.y;
                    vxy[0].x += g * pxy.x;  vxy[0].y += g * pxy.y;
                }
                if (k > 0) {
                    const float g = win.g[k - 1];
                    vx[1].x  += g * xv.x;   vx[1].y  += g * xv.y;
                    vy[1].x  += g * yv.x;   vy[1].y  += g * yv.y;
                    vxx[1].x += g * pxx.x;  vxx[1].y += g * pxx.y;
                    vyy[1].x += g * pyy.x;  vyy[1].y += g * pyy.y;
                    vxy[1].x += g * pxy.x;  vxy[1].y += g * pxy.y;
                }
            }
#pragma unroll
            for (int r = 0; r < 2; ++r) {
                float* hb = &hbuf[r][0][0];
                *(float2*)&hb[0 * PSTR + 6 + c0] = vx[r];
                *(float2*)&hb[1 * PSTR + 6 + c0] = vy[r];
                *(float2*)&hb[2 * PSTR + 6 + c0] = vxx[r];
                *(float2*)&hb[3 * PSTR + 6 + c0] = vyy[r];
                *(float2*)&hb[4 * PSTR + 6 + c0] = vxy[r];
            }
        }

        __syncthreads();

        // horizontal 11-tap conv: rw = tid>>7 (row), q = tid&127 (4 cols), b128
        {
            const int rw = tid >> 7;
            const int q  = tid & 127;
            float m[5][4];
#pragma unroll
            for (int f = 0; f < 5; ++f) {
                const float4* rowv = (const float4*)&hbuf[rw][f][0];
                float4 a = rowv[q];
                float4 b = rowv[q + 1];
                float4 c = rowv[q + 2];
                float4 d = rowv[q + 3];
                float w16[16] = { a.x, a.y, a.z, a.w,  b.x, b.y, b.z, b.w,
                                  c.x, c.y, c.z, c.w,  d.x, d.y, d.z, d.w };
#pragma unroll
                for (int j = 0; j < 4; ++j) {
                    float s = 0.f;
#pragma unroll
                    for (int k = 0; k < 11; ++k) s += win.g[k] * w16[j + k + 1];
                    m[f][j] = s;
                }
            }
#pragma unroll
            for (int u = 0; u < 4; ++u) {
                float mx  = m[0][u];
                float my  = m[1][u];
                float mxx = m[2][u];
                float myy = m[3][u];
                float mxy = m[4][u];
                float mu_x_sq = mx * mx;
                float mu_y_sq = my * my;
                float mu_xy   = mx * my;
                float sig_x  = mxx - mu_x_sq;
                float sig_y  = myy - mu_y_sq;
                float sig_xy = mxy - mu_xy;
                const float C1 = 0.01f * 0.01f;
                const float C2 = 0.03f * 0.03f;
                float n = (2.f * mu_xy + C1) * (2.f * sig_xy + C2);
                float d = (mu_x_sq + mu_y_sq + C1) * (sig_x + sig_y + C2);
                lsum += n / (d + 1e-8f);
            }
        }

        __syncthreads();   // protect hbuf before next pair's writes

        // shift ring down by 2 (static indices)
#pragma unroll
        for (int k = 0; k < 10; ++k) { xr[k] = xr[k + 2]; yr[k] = yr[k + 2]; }
    }

    // block reduction
#pragma unroll
    for (int off = 32; off; off >>= 1) lsum += __shfl_down(lsum, off);
    if ((tid & 63) == 0) wsum[tid >> 6] = lsum;
    __syncthreads();
    if (tid == 0)
        atomicAdd(accum, (double)(wsum[0] + wsum[1] + wsum[2] + wsum[3]));
}

__global__ void ssim_finalize_kernel(const double* __restrict__ accum,
                                     float* __restrict__ out)
{
    out[0] = (float)(accum[0] / (double)TOTAL_PIX);
}

extern "C" void kernel_launch(void* const* d_in, const int* in_sizes, int n_in,
                              void* d_out, int out_size, void* d_ws, size_t ws_size,
                              hipStream_t stream) {
    const float* x = (const float*)d_in[0];
    const float* y = (const float*)d_in[1];
    float* out = (float*)d_out;
    double* accum = (double*)d_ws;

    GWin win;
    {
        double g[11], s = 0.0;
        for (int i = 0; i < 11; ++i) {
            double d = (double)i - 5.0;
            g[i] = std::exp(-(d * d) / (2.0 * 1.5 * 1.5));
            s += g[i];
        }
        for (int i = 0; i < 11; ++i) win.g[i] = (float)(g[i] / s);
    }

    hipMemsetAsync(d_ws, 0, sizeof(double), stream);

    const int nblocks = PLANES * BANDS;  // 1536
    ssim_pair_kernel<<<nblocks, 256, 0, stream>>>(x, y, accum, win);
    ssim_finalize_kernel<<<1, 1, 0, stream>>>(accum, out);
}